// Round 7
// baseline (142.294 us; speedup 1.0000x reference)
//
#include <hip/hip_runtime.h>
#include <hip/hip_bf16.h>
#include <hip/hip_cooperative_groups.h>
#include <math.h>

namespace cg = cooperative_groups;

#define P 4096          // number of (even,odd) pairs = B/2
#define DIM 128
#define MARGIN_F 1.0f
#define EPS_F 1e-8f

#define ROWS_PER_BLOCK 128    // 4 waves x 32 rows
#define COLS_PER_BLOCK 256    // 4 tiles of 64 cols
#define TILE_COLS 64
#define NTILES 4
#define NBLOCKS 512           // 2 blocks/CU -> co-resident (256 thr, 32KB LDS)

typedef float f32x4 __attribute__((ext_vector_type(4)));
typedef short bf16x8 __attribute__((ext_vector_type(8)));

static __device__ __forceinline__ void gload_lds16(const void* g, void* l) {
    __builtin_amdgcn_global_load_lds(
        (const __attribute__((address_space(1))) void*)g,
        (__attribute__((address_space(3))) void*)l,
        16, 0, 0);
}

static __device__ __forceinline__ short f2bf(float f) {
    return __builtin_bit_cast(short, __float2bfloat16(f));
}

static __device__ __forceinline__ bf16x8 cvt8(f32x4 lo, f32x4 hi, float s) {
    bf16x8 r;
    r[0] = f2bf(lo[0] * s); r[1] = f2bf(lo[1] * s);
    r[2] = f2bf(lo[2] * s); r[3] = f2bf(lo[3] * s);
    r[4] = f2bf(hi[0] * s); r[5] = f2bf(hi[1] * s);
    r[6] = f2bf(hi[2] * s); r[7] = f2bf(hi[3] * s);
    return r;
}

// Phase A: convert odd rows of x to bf16 (xo), zero rowsum/colsum/out.
// 131072 float4s over 512 blocks -> exactly 1 per thread.
static __device__ __forceinline__ void phaseA(
    const float* x, short* xo, float* rowcol, float* out) {

    const int i = blockIdx.x * 256 + threadIdx.x;   // < 131072
    const int orow = i >> 5;                        // odd-row index
    const int c4 = i & 31;
    f32x4 v = *reinterpret_cast<const f32x4*>(
        x + (size_t)(2 * orow + 1) * DIM + c4 * 4);
    short4 pk;
    pk.x = f2bf(v[0]); pk.y = f2bf(v[1]); pk.z = f2bf(v[2]); pk.w = f2bf(v[3]);
    *reinterpret_cast<short4*>(&xo[(size_t)orow * DIM + c4 * 4]) = pk;

    if (i < 2 * P) rowcol[i] = 0.0f;
    if (i == 0) out[0] = 0.0f;
}

// Phase B: M[p,k] = exp(1 + dot(x[2p]/128, xo[k])); rowsum[p] += over k,
// colsum[k] += over p. A (128x128) converted fp32->bf16 in registers; B
// double-buffered in LDS (gload_lds w16, pre-swizzled source), 2-phase
// pipeline with one barrier per tile.
static __device__ __forceinline__ void phaseB(
    const float* x, const short* xo, float* rowsum, float* colsum) {

    __shared__ __align__(16) short Bs[2][TILE_COLS * DIM];   // 2 x 16 KB

    const int tid = threadIdx.x;
    const int lane = tid & 63;
    const int wave = tid >> 6;
    const int p0 = (blockIdx.x >> 4) * ROWS_PER_BLOCK;   // 32 row-blocks
    const int c0 = (blockIdx.x & 15) * COLS_PER_BLOCK;   // 16 col-blocks
    const int lrow = lane & 15;
    const int kgrp = (lane >> 4) * 8;   // k offset in shorts

    const char* gB = (const char*)(xo + (size_t)c0 * DIM);
    auto stage = [&](int t) {
        char* lB = (char*)Bs[t & 1];
        const char* gt = gB + (size_t)t * (TILE_COLS * DIM * 2);
        #pragma unroll
        for (int i = 0; i < 4; ++i) {           // 16 KB = 16 x 1 KB chunks
            int Lbase = (wave * 4 + i) * 1024;  // wave-uniform LDS dest
            int L = Lbase + lane * 16;
            int src = L ^ (((L >> 8) & 7) << 4);  // inverse swizzle (involution)
            gload_lds16(gt + src, lB + Lbase);
        }
    };
    stage(0);

    // A fragments: rows 2*(p0 + wave*32 + m*16 + lrow) of x, scaled 1/128,
    // converted to bf16 in registers (exact: power-of-2 scale).
    bf16x8 a[2][4];
    #pragma unroll
    for (int m = 0; m < 2; ++m) {
        const float* arow =
            x + (size_t)(2 * (p0 + wave * 32 + m * 16 + lrow)) * DIM + kgrp;
        #pragma unroll
        for (int k32 = 0; k32 < 4; ++k32) {
            f32x4 lo = *reinterpret_cast<const f32x4*>(arow + k32 * 32);
            f32x4 hi = *reinterpret_cast<const f32x4*>(arow + k32 * 32 + 4);
            a[m][k32] = cvt8(lo, hi, 0.0078125f);
        }
    }

    float rs[2][4];        // row partials [m][j], row = w*32+m*16+g*4+j
    float cpp[NTILES][4];  // col partials [t][n] (static idx via unroll)
    #pragma unroll
    for (int m = 0; m < 2; ++m)
        #pragma unroll
        for (int j = 0; j < 4; ++j) rs[m][j] = 0.0f;
    #pragma unroll
    for (int t = 0; t < NTILES; ++t)
        #pragma unroll
        for (int n = 0; n < 4; ++n) cpp[t][n] = 0.0f;

    #pragma unroll
    for (int t = 0; t < NTILES; ++t) {
        // Barrier: (a) vmcnt drains -> stage(t) landed; (b) all waves done
        // with compute(t-1), so Bs[(t+1)&1] is safe to overwrite.
        __syncthreads();
        if (t + 1 < NTILES) stage(t + 1);   // in flight across compute(t)

        const short* B = Bs[t & 1];
        f32x4 acc[2][4];
        #pragma unroll
        for (int m = 0; m < 2; ++m)
            #pragma unroll
            for (int n = 0; n < 4; ++n) acc[m][n] = f32x4{0.f, 0.f, 0.f, 0.f};

        #pragma unroll
        for (int k32 = 0; k32 < 4; ++k32) {
            #pragma unroll
            for (int n = 0; n < 4; ++n) {
                int cc = n * 16 + lrow;
                int idx = (cc * DIM + k32 * 32 + kgrp) ^ ((cc & 7) << 3);
                bf16x8 b = *reinterpret_cast<const bf16x8*>(&B[idx]);
                #pragma unroll
                for (int m = 0; m < 2; ++m)
                    acc[m][n] = __builtin_amdgcn_mfma_f32_16x16x32_bf16(
                        a[m][k32], b, acc[m][n], 0, 0, 0);
            }
        }

        // Epilogue: exp, all partials in registers.
        // C/D layout: col = lane&15, row = (lane>>4)*4 + j (m89/m91).
        #pragma unroll
        for (int n = 0; n < 4; ++n)
            #pragma unroll
            for (int m = 0; m < 2; ++m)
                #pragma unroll
                for (int j = 0; j < 4; ++j) {
                    float e = __expf(MARGIN_F + acc[m][n][j]);
                    rs[m][j] += e;
                    cpp[t][n] += e;
                }
    }

    // Row sums: reduce across the 16 col-lanes of each lane-group.
    #pragma unroll
    for (int m = 0; m < 2; ++m)
        #pragma unroll
        for (int j = 0; j < 4; ++j) {
            float v = rs[m][j];
            v += __shfl_xor(v, 1);
            v += __shfl_xor(v, 2);
            v += __shfl_xor(v, 4);
            v += __shfl_xor(v, 8);
            rs[m][j] = v;
        }
    if (lrow == 0) {
        int g = lane >> 4;
        #pragma unroll
        for (int m = 0; m < 2; ++m)
            #pragma unroll
            for (int j = 0; j < 4; ++j)
                atomicAdd(&rowsum[p0 + wave * 32 + m * 16 + g * 4 + j],
                          rs[m][j]);
    }

    // Col sums: reduce across the 4 row-groups, one atomic per col per wave.
    #pragma unroll
    for (int t = 0; t < NTILES; ++t)
        #pragma unroll
        for (int n = 0; n < 4; ++n) {
            float v = cpp[t][n];
            v += __shfl_xor(v, 16);
            v += __shfl_xor(v, 32);
            if (lane < 16)
                atomicAdd(&colsum[c0 + t * TILE_COLS + n * 16 + lane], v);
        }
}

// Phase C: per-p corrections + J + loss (fp32 exact). 8 pairs per block.
static __device__ __forceinline__ void phaseC(
    const float* x, const float* rowsum, const float* colsum, float* out) {

    __shared__ float wsum[4];
    const int tid = threadIdx.x;
    const int wave = tid >> 6;
    const int lane = tid & 63;

    float racc = 0.0f;
    #pragma unroll
    for (int q = 0; q < 2; ++q) {
        const int p = blockIdx.x * 8 + wave * 2 + q;

        const float2* xep = reinterpret_cast<const float2*>(x + (size_t)(2 * p) * DIM);
        const float2* xop = reinterpret_cast<const float2*>(x + (size_t)(2 * p + 1) * DIM);
        float2 ve = xep[lane];
        float2 vo = xop[lane];
        float dpos = ve.x * vo.x + ve.y * vo.y;

        float ci = 0.0f, cj = 0.0f;
        if (p < P / 2) {
            const float2* xi = reinterpret_cast<const float2*>(x + (size_t)(4 * p + 3) * DIM);
            const float2* xj = reinterpret_cast<const float2*>(x + (size_t)(4 * p) * DIM);
            float2 vi = xi[lane];
            float2 vj = xj[lane];
            ci = ve.x * vi.x + ve.y * vi.y;   // dot(x[2p],   x[4p+3])
            cj = vo.x * vj.x + vo.y * vj.y;   // dot(x[2p+1], x[4p])
        }

        #pragma unroll
        for (int off = 32; off > 0; off >>= 1) {
            dpos += __shfl_down(dpos, off);
            ci   += __shfl_down(ci, off);
            cj   += __shfl_down(cj, off);
        }

        if (lane == 0) {
            float corr = 0.0f;
            if (p < P / 2)
                corr = __expf(MARGIN_F + ci * (1.0f / 128.0f))
                     + __expf(MARGIN_F + cj * (1.0f / 128.0f));
            float neg = rowsum[p] + colsum[p] - corr;
            float J = logf(EPS_F + neg) - dpos * (1.0f / 128.0f);
            float r = fmaxf(J, 0.0f);
            racc += r * r;
        }
    }

    if (lane == 0) wsum[wave] = racc;
    __syncthreads();
    if (tid == 0) {
        float s = (wsum[0] + wsum[1] + wsum[2] + wsum[3]) * (1.0f / 8192.0f);
        atomicAdd(out, s);
    }
}

// PHASES bitmask: 1=convert, 2=gram, 4=finalize. Only the full <7>
// instantiation calls grid.sync() and must be launched cooperatively.
template <int PHASES>
__global__ __launch_bounds__(256, 2) void fused_t(
    const float* x, short* xo, float* rowsum, float* colsum, float* out) {

    if (PHASES & 1) phaseA(x, xo, rowsum, out);
    if (PHASES == 7) cg::this_grid().sync();
    if (PHASES & 2) phaseB(x, xo, rowsum, colsum);
    if (PHASES == 7) cg::this_grid().sync();
    if (PHASES & 4) phaseC(x, rowsum, colsum, out);
}

extern "C" void kernel_launch(void* const* d_in, const int* in_sizes, int n_in,
                              void* d_out, int out_size, void* d_ws, size_t ws_size,
                              hipStream_t stream) {
    const float* x = (const float*)d_in[0];
    float* rowsum = (float*)d_ws;
    float* colsum = rowsum + P;
    short* xo = (short*)(colsum + P);
    float* outp = (float*)d_out;

    void* args[] = {(void*)&x, (void*)&xo, (void*)&rowsum, (void*)&colsum,
                    (void*)&outp};
    hipError_t err = hipLaunchCooperativeKernel(
        reinterpret_cast<void*>(fused_t<7>), dim3(NBLOCKS), dim3(256),
        args, 0, stream);
    if (err != hipSuccess) {
        // Fallback: same phases as three stream-ordered launches (no grid.sync).
        fused_t<1><<<NBLOCKS, 256, 0, stream>>>(x, xo, rowsum, colsum, outp);
        fused_t<2><<<NBLOCKS, 256, 0, stream>>>(x, xo, rowsum, colsum, outp);
        fused_t<4><<<NBLOCKS, 256, 0, stream>>>(x, xo, rowsum, colsum, outp);
    }
}

// Round 8
// 35.547 us; speedup vs baseline: 4.0030x; 4.0030x over previous
//
#include <hip/hip_runtime.h>
#include <hip/hip_bf16.h>
#include <math.h>

#define P 4096          // number of (even,odd) pairs = B/2
#define DIM 128
#define EPS_F 1e-8f
#define LOG2E 1.4426950408889634f
#define MLG2 1.4426950408889634f   // MARGIN(=1) * log2e, folded into acc init

#define RPB 128         // rows per block (4 waves x 32)
#define CPB 128         // cols per block (2 tiles of 64)
#define TILE_COLS 64
#define NTILES 2
#define NRB (P / RPB)   // 32 row-blocks
#define NCB (P / CPB)   // 32 col-blocks

typedef float f32x4 __attribute__((ext_vector_type(4)));
typedef short bf16x8 __attribute__((ext_vector_type(8)));

static __device__ __forceinline__ short f2bf(float f) {
    return __builtin_bit_cast(short, __float2bfloat16(f));
}

static __device__ __forceinline__ bf16x8 cvt8s(f32x4 lo, f32x4 hi, float s) {
    bf16x8 r;
    r[0] = f2bf(lo[0] * s); r[1] = f2bf(lo[1] * s);
    r[2] = f2bf(lo[2] * s); r[3] = f2bf(lo[3] * s);
    r[4] = f2bf(hi[0] * s); r[5] = f2bf(hi[1] * s);
    r[6] = f2bf(hi[2] * s); r[7] = f2bf(hi[3] * s);
    return r;
}

// Gram kernel: M[p,k] = exp2(log2e*(1+dot(x[2p],x[2k+1])/128)) = exp(1+D).
// Row partials -> pr[cb][p], col partials -> pc[rb][k] (no atomics, no init).
// B tiles staged from fp32 x with in-reg convert + swizzled ds_write;
// 2-phase pipeline, one barrier per tile.
__global__ __launch_bounds__(256, 4) void gram_mfma(
    const float* __restrict__ x,
    float* __restrict__ pr,     // [NCB][P] row partials
    float* __restrict__ pc,     // [NRB][P] col partials
    float* __restrict__ out) {

    __shared__ __align__(16) short Bs[2][TILE_COLS * DIM];   // 2 x 16 KB

    const int tid = threadIdx.x;
    const int lane = tid & 63;
    const int wave = tid >> 6;
    const int rb = blockIdx.y, cb = blockIdx.x;
    const int p0 = rb * RPB;
    const int c0 = cb * CPB;
    const int lrow = lane & 15;
    const int kgrp = (lane >> 4) * 8;   // k offset in shorts

    if (rb == 0 && cb == 0 && tid == 0) out[0] = 0.0f;   // stream-ordered vs finalize

    // Stage tile t (cols c0+t*64.. , odd rows of x): fp32 load, bf16 convert,
    // swizzled ds_write_b128 (granule XOR (r&7)<<3 in shorts).
    auto stage = [&](int t) {
        short* lB = Bs[t & 1];
        const int r = tid >> 2;            // 0..63
        const int kq = (tid & 3) * 32;     // k quarter
        const float* src = x + (size_t)(2 * (c0 + t * TILE_COLS + r) + 1) * DIM + kq;
        #pragma unroll
        for (int u = 0; u < 4; ++u) {
            f32x4 lo = *reinterpret_cast<const f32x4*>(src + u * 8);
            f32x4 hi = *reinterpret_cast<const f32x4*>(src + u * 8 + 4);
            bf16x8 v = cvt8s(lo, hi, 1.0f);
            int idx = (r * DIM + kq + u * 8) ^ ((r & 7) << 3);
            *reinterpret_cast<bf16x8*>(&lB[idx]) = v;
        }
    };
    stage(0);

    // A fragments: even rows of x, scaled log2e/128, converted in registers.
    bf16x8 a[2][4];
    #pragma unroll
    for (int m = 0; m < 2; ++m) {
        const float* arow =
            x + (size_t)(2 * (p0 + wave * 32 + m * 16 + lrow)) * DIM + kgrp;
        #pragma unroll
        for (int k32 = 0; k32 < 4; ++k32) {
            f32x4 lo = *reinterpret_cast<const f32x4*>(arow + k32 * 32);
            f32x4 hi = *reinterpret_cast<const f32x4*>(arow + k32 * 32 + 4);
            a[m][k32] = cvt8s(lo, hi, LOG2E / 128.0f);
        }
    }

    float rs[2][4];        // row partials [m][j]
    float cpp[NTILES][4];  // col partials [t][n]
    #pragma unroll
    for (int m = 0; m < 2; ++m)
        #pragma unroll
        for (int j = 0; j < 4; ++j) rs[m][j] = 0.0f;
    #pragma unroll
    for (int t = 0; t < NTILES; ++t)
        #pragma unroll
        for (int n = 0; n < 4; ++n) cpp[t][n] = 0.0f;

    #pragma unroll
    for (int t = 0; t < NTILES; ++t) {
        __syncthreads();                      // stage(t) visible; buffers safe
        if (t + 1 < NTILES) stage(t + 1);     // overlaps compute(t)

        const short* B = Bs[t & 1];
        f32x4 acc[2][4];
        #pragma unroll
        for (int m = 0; m < 2; ++m)
            #pragma unroll
            for (int n = 0; n < 4; ++n)
                acc[m][n] = f32x4{MLG2, MLG2, MLG2, MLG2};   // margin folded in

        #pragma unroll
        for (int k32 = 0; k32 < 4; ++k32) {
            #pragma unroll
            for (int n = 0; n < 4; ++n) {
                int cc = n * 16 + lrow;
                int idx = (cc * DIM + k32 * 32 + kgrp) ^ ((cc & 7) << 3);
                bf16x8 b = *reinterpret_cast<const bf16x8*>(&B[idx]);
                #pragma unroll
                for (int m = 0; m < 2; ++m)
                    acc[m][n] = __builtin_amdgcn_mfma_f32_16x16x32_bf16(
                        a[m][k32], b, acc[m][n], 0, 0, 0);
            }
        }

        // exp2 epilogue (arg already = log2e*(1+D)); partials in registers.
        // C/D layout: col = lane&15, row = (lane>>4)*4 + j (m89/m91).
        #pragma unroll
        for (int n = 0; n < 4; ++n)
            #pragma unroll
            for (int m = 0; m < 2; ++m)
                #pragma unroll
                for (int j = 0; j < 4; ++j) {
                    float e = exp2f(acc[m][n][j]);
                    rs[m][j] += e;
                    cpp[t][n] += e;
                }
    }

    // Row sums: reduce across the 16 col-lanes of each lane-group; plain store.
    #pragma unroll
    for (int m = 0; m < 2; ++m)
        #pragma unroll
        for (int j = 0; j < 4; ++j) {
            float v = rs[m][j];
            v += __shfl_xor(v, 1);
            v += __shfl_xor(v, 2);
            v += __shfl_xor(v, 4);
            v += __shfl_xor(v, 8);
            rs[m][j] = v;
        }
    if (lrow == 0) {
        int g = lane >> 4;
        #pragma unroll
        for (int m = 0; m < 2; ++m)
            #pragma unroll
            for (int j = 0; j < 4; ++j)
                pr[(size_t)cb * P + p0 + wave * 32 + m * 16 + g * 4 + j] =
                    rs[m][j];
    }

    // Col sums: shfl over row-groups, combine 4 waves via LDS (reuse Bs),
    // then one plain store per col.
    __syncthreads();   // all ds_reads of Bs done before reuse
    float* csf = reinterpret_cast<float*>(&Bs[0][0]);   // 4 x 128 floats
    #pragma unroll
    for (int t = 0; t < NTILES; ++t)
        #pragma unroll
        for (int n = 0; n < 4; ++n) {
            float v = cpp[t][n];
            v += __shfl_xor(v, 16);
            v += __shfl_xor(v, 32);
            if (lane < 16)
                csf[wave * CPB + t * TILE_COLS + n * 16 + lane] = v;
        }
    __syncthreads();
    if (tid < CPB)
        pc[(size_t)rb * P + c0 + tid] =
            csf[tid] + csf[CPB + tid] + csf[2 * CPB + tid] + csf[3 * CPB + tid];
}

// Finalize: gather partials, fp32 corrections/dpos, J, loss. 1 thread per p.
__global__ __launch_bounds__(128) void finalize(
    const float* __restrict__ x,
    const float* __restrict__ pr,
    const float* __restrict__ pc,
    float* __restrict__ out) {

    __shared__ float wsum[2];
    const int tid = threadIdx.x;
    const int lane = tid & 63;
    const int wave = tid >> 6;
    const int p = blockIdx.x * 128 + tid;   // grid = 32 -> p in [0,P)

    float rsum = 0.0f, csum = 0.0f;
    #pragma unroll 8
    for (int b = 0; b < NCB; ++b) rsum += pr[(size_t)b * P + p];
    #pragma unroll 8
    for (int b = 0; b < NRB; ++b) csum += pc[(size_t)b * P + p];

    const bool has = p < P / 2;
    const f32x4* xe4 = reinterpret_cast<const f32x4*>(x + (size_t)(2 * p) * DIM);
    const f32x4* xo4 = reinterpret_cast<const f32x4*>(x + (size_t)(2 * p + 1) * DIM);
    const f32x4* xi4 = reinterpret_cast<const f32x4*>(
        x + (size_t)(has ? 4 * p + 3 : 1) * DIM);
    const f32x4* xj4 = reinterpret_cast<const f32x4*>(
        x + (size_t)(has ? 4 * p : 0) * DIM);

    float dpos = 0.0f, ci = 0.0f, cj = 0.0f;
    #pragma unroll 4
    for (int i = 0; i < DIM / 4; ++i) {
        f32x4 e = xe4[i], o = xo4[i], vi = xi4[i], vj = xj4[i];
        #pragma unroll
        for (int u = 0; u < 4; ++u) {
            dpos += e[u] * o[u];
            ci   += e[u] * vi[u];
            cj   += o[u] * vj[u];
        }
    }

    float corr = 0.0f;
    if (has)
        corr = __expf(1.0f + ci * (1.0f / 128.0f))
             + __expf(1.0f + cj * (1.0f / 128.0f));
    float neg = rsum + csum - corr;
    float J = logf(EPS_F + neg) - dpos * (1.0f / 128.0f);
    float r = fmaxf(J, 0.0f);
    r = r * r;

    #pragma unroll
    for (int off = 32; off > 0; off >>= 1) r += __shfl_down(r, off);
    if (lane == 0) wsum[wave] = r;
    __syncthreads();
    if (tid == 0)
        atomicAdd(out, (wsum[0] + wsum[1]) * (1.0f / 8192.0f));
}

extern "C" void kernel_launch(void* const* d_in, const int* in_sizes, int n_in,
                              void* d_out, int out_size, void* d_ws, size_t ws_size,
                              hipStream_t stream) {
    const float* x = (const float*)d_in[0];
    float* pr = (float*)d_ws;            // 32*4096 floats
    float* pc = pr + (size_t)NCB * P;    // 32*4096 floats
    float* outp = (float*)d_out;

    dim3 grid(NCB, NRB);   // (32, 32) = 1024 blocks
    gram_mfma<<<grid, 256, 0, stream>>>(x, pr, pc, outp);
    finalize<<<P / 128, 128, 0, stream>>>(x, pr, pc, outp);
}